// Round 7
// baseline (440.146 us; speedup 1.0000x reference)
//
#include <hip/hip_runtime.h>
#include <cstdint>
#include <cstddef>

#define BN_   4
#define CC    96
#define C2    192
#define NN    3136
#define KNN   9
#define TILE  64
#define PT    8
#define NCH   8   // column chunks for k_dist

typedef __attribute__((ext_vector_type(8))) __bf16 bf16x8;
typedef __attribute__((ext_vector_type(4))) float f32x4;

__device__ __forceinline__ unsigned short f2bf(float f) {
  unsigned int u = __float_as_uint(f);
  unsigned int r = u + 0x7fffu + ((u >> 16) & 1u);   // RNE
  return (unsigned short)(r >> 16);
}
__device__ __forceinline__ float bf2f(unsigned short h) {
  return __uint_as_float(((unsigned int)h) << 16);
}
// monotone map: fmono(a) > fmono(b)  <=>  a > b  (as floats)
__device__ __forceinline__ unsigned int fmono(float f) {
  unsigned int s = __float_as_uint(f);
  return s ^ ((unsigned int)((int)s >> 31) | 0x80000000u);
}
// branchless sorted-ascending top-9 insert: ~17 v_min/v_max_u32, no branches
__device__ __forceinline__ void chain9(unsigned int key, unsigned int (&bv)[KNN]) {
  unsigned int c = key > bv[0] ? key : bv[0];
  #pragma unroll
  for (int j = 1; j < KNN; ++j) {
    unsigned int lo = c < bv[j] ? c : bv[j];
    unsigned int hi = c < bv[j] ? bv[j] : c;
    bv[j - 1] = lo; c = hi;
  }
  bv[KNN - 1] = c;
}
// u64 (key<<32 | ~col) top-9, unordered + cached min (branchy; small streams)
__device__ __forceinline__ void topk_u64(uint64_t key, uint64_t (&bk)[KNN],
                                         uint64_t& mnk, int& mns) {
  if (key > mnk) {
    #pragma unroll
    for (int j = 0; j < KNN; ++j) if (j == mns) bk[j] = key;
    mnk = bk[0]; mns = 0;
    #pragma unroll
    for (int j = 1; j < KNN; ++j) if (bk[j] < mnk) { mnk = bk[j]; mns = j; }
  }
}

// ---------------------------------------------------------------------------
// K1: y1t[b][n][o] = bn1(fc1_w @ x + fc1_b).  BIT-EXACT R4 version.
// DO NOT change the arithmetic/order here: xh/xl/sq feed a discrete top-k;
// any ulp change can flip a neighbor (verified: R5/R6 fused-norm failure).
// ---------------------------------------------------------------------------
__global__ __launch_bounds__(256) void k_fc1(const float* __restrict__ x,
                                             const float* __restrict__ w,
                                             const float* __restrict__ bias,
                                             const float* __restrict__ bn,
                                             float* __restrict__ y1t) {
  __shared__ float xs[CC * 64];  // [c][64]
  const int b = blockIdx.y, n0 = blockIdx.x * 64;
  const int t = threadIdx.x;
  for (int i = t; i < CC * 64; i += 256) {
    int c = i >> 6, nn = i & 63;
    xs[i] = x[((size_t)b * CC + c) * NN + n0 + nn];
  }
  __syncthreads();
  const int nn = t & 63;
  const int og = __builtin_amdgcn_readfirstlane(t >> 6);
  float acc[24];
  #pragma unroll
  for (int i = 0; i < 24; ++i) acc[i] = 0.f;
  for (int c = 0; c < CC; ++c) {
    float xv = xs[c * 64 + nn];
    const float* wp = w + (size_t)(og * 24) * CC + c;
    #pragma unroll
    for (int oi = 0; oi < 24; ++oi) acc[oi] = fmaf(wp[oi * CC], xv, acc[oi]);
  }
  #pragma unroll
  for (int oi = 0; oi < 24; ++oi) {
    int o = og * 24 + oi;
    float g = bn[o], be = bn[CC + o], mn = bn[2 * CC + o], vr = bn[3 * CC + o];
    float inv = g / sqrtf(vr + 1e-5f);
    float v = fmaf(acc[oi] + bias[o], inv, be - mn * inv);
    y1t[((size_t)b * NN + n0 + nn) * CC + o] = v;
  }
}

// ---------------------------------------------------------------------------
// K2: per-position L2 norm; bf16 split (hi, lo) + sq.  BIT-EXACT R4 version.
// ---------------------------------------------------------------------------
__global__ __launch_bounds__(256) void k_norm(const float* __restrict__ y1t,
                                              unsigned short* __restrict__ xh,
                                              unsigned short* __restrict__ xl,
                                              float* __restrict__ sq) {
  const int p = blockIdx.x * 256 + threadIdx.x;  // 49*256 == 12544 exactly
  const float* row = y1t + (size_t)p * CC;
  float s = 0.f;
  for (int c = 0; c < CC; c += 4) {
    float4 v = *(const float4*)(row + c);
    s += v.x * v.x; s += v.y * v.y; s += v.z * v.z; s += v.w * v.w;
  }
  float inv = 1.f / fmaxf(sqrtf(s), 1e-12f);
  float sqs = 0.f;
  unsigned short* hrow = xh + (size_t)p * CC;
  unsigned short* lrow = xl + (size_t)p * CC;
  for (int c = 0; c < CC; ++c) {
    float v = row[c] * inv;
    sqs += v * v;
    unsigned short h = f2bf(v);
    float lo = v - bf2f(h);
    hrow[c] = h;
    lrow[c] = f2bf(lo);
  }
  sq[p] = sqs;
}

// ---------------------------------------------------------------------------
// K3: two-pass kNN.  Pass 1: branchless value-only top-9 (u32 min/max chain),
// B staged in LDS.  Pass 2: recompute (bitwise-identical MFMA) with B read
// from global; collect EXACT selection into 9 per-lane LDS slots:
//   strictly-greater keys fill from the front (<=8, never dropped),
//   ==theta keys fill from the back in ascending-col order (smallest cols
//   kept; largest-col theta evicted when a later greater needs room).
// Reproduces jax (value desc, idx asc) exactly, duplicates included.
// ---------------------------------------------------------------------------
__global__ __launch_bounds__(256) void k_dist(const unsigned short* __restrict__ xh,
                                              const unsigned short* __restrict__ xl,
                                              const float* __restrict__ sq,
                                              uint64_t* __restrict__ cand_k) {
  __shared__ __align__(16) unsigned short sB[2 * 64 * 104];  // 26624 B
  __shared__ __align__(16) float sqm[TILE];
  unsigned short* BsH = sB;
  unsigned short* BsL = sB + 64 * 104;
  uint64_t* sk = (uint64_t*)sB;   // pass-2 hit slots alias sB (dead then)

  const int rt = blockIdx.x, chunk = blockIdx.y, b = blockIdx.z;
  const int r0 = rt * TILE;
  const int t = threadIdx.x;
  const int lane = t & 63, w = t >> 6;
  const int m16 = lane & 15, quad = lane >> 4;
  const int mt0 = (49 * chunk) / NCH, mt1 = (49 * (chunk + 1)) / NCH;

  const int gr = r0 + w * 16 + m16;
  bf16x8 ah[3], al[3];
  {
    const unsigned short* pH = xh + ((size_t)b * NN + gr) * CC + quad * 8;
    const unsigned short* pL = xl + ((size_t)b * NN + gr) * CC + quad * 8;
    #pragma unroll
    for (int kc = 0; kc < 3; ++kc) {
      ah[kc] = *(const bf16x8*)(pH + kc * 32);
      al[kc] = *(const bf16x8*)(pL + kc * 32);
    }
  }
  const float sr = sq[b * NN + gr];

  unsigned int bv[KNN];
  #pragma unroll
  for (int j = 0; j < KNN; ++j) bv[j] = 0u;

  // ---- pass 1 ----
  const int srow_ = t >> 2, sch = t & 3;   // pow2 staging map
  for (int mt = mt0; mt < mt1; ++mt) {
    const int m0 = mt * TILE;
    __syncthreads();
    {
      const size_t rbase = ((size_t)b * NN + m0 + srow_) * CC;
      #pragma unroll
      for (int it = 0; it < 3; ++it) {
        int ch = sch + (it << 2);
        *(uint4*)&BsH[srow_ * 104 + ch * 8] = *(const uint4*)(xh + rbase + ch * 8);
        *(uint4*)&BsL[srow_ * 104 + ch * 8] = *(const uint4*)(xl + rbase + ch * 8);
      }
    }
    if (t < TILE) sqm[t] = sq[b * NN + m0 + t];
    __syncthreads();

    #pragma unroll
    for (int tt = 0; tt < 4; ++tt) {
      const int brow = (tt * 16 + m16) * 104 + quad * 8;
      f32x4 acc = {0.f, 0.f, 0.f, 0.f};
      #pragma unroll
      for (int kc = 0; kc < 3; ++kc) {
        bf16x8 bh = *(const bf16x8*)&BsH[brow + kc * 32];
        bf16x8 bl = *(const bf16x8*)&BsL[brow + kc * 32];
        acc = __builtin_amdgcn_mfma_f32_16x16x32_bf16(bh, ah[kc], acc, 0, 0, 0);
        acc = __builtin_amdgcn_mfma_f32_16x16x32_bf16(bl, ah[kc], acc, 0, 0, 0);
        acc = __builtin_amdgcn_mfma_f32_16x16x32_bf16(bh, al[kc], acc, 0, 0, 0);
      }
      float4 s4 = *(const float4*)&sqm[tt * 16 + quad * 4];
      const float sv[4] = {s4.x, s4.y, s4.z, s4.w};
      #pragma unroll
      for (int r = 0; r < 4; ++r) {
        float v = fmaf(2.f, acc[r], -sr) - sv[r];
        chain9(fmono(v), bv);
      }
    }
  }
  __syncthreads();   // all pass-1 LDS reads done before sk aliases sB

  // ---- pass 2 ----
  const unsigned int theta = bv[0];
  uint64_t* myslots = sk + ((size_t)(w * 16 + m16) * 4 + quad) * KNN;
  #pragma unroll
  for (int j = 0; j < KNN; ++j) myslots[j] = 0ull;
  int cntg = 0, cntt = 0;
  for (int mt = mt0; mt < mt1; ++mt) {
    const int m0 = mt * TILE;
    #pragma unroll
    for (int tt = 0; tt < 4; ++tt) {
      const size_t brbase = ((size_t)b * NN + m0 + tt * 16 + m16) * CC + quad * 8;
      f32x4 acc = {0.f, 0.f, 0.f, 0.f};
      #pragma unroll
      for (int kc = 0; kc < 3; ++kc) {
        bf16x8 bh = *(const bf16x8*)(xh + brbase + kc * 32);
        bf16x8 bl = *(const bf16x8*)(xl + brbase + kc * 32);
        acc = __builtin_amdgcn_mfma_f32_16x16x32_bf16(bh, ah[kc], acc, 0, 0, 0);
        acc = __builtin_amdgcn_mfma_f32_16x16x32_bf16(bl, ah[kc], acc, 0, 0, 0);
        acc = __builtin_amdgcn_mfma_f32_16x16x32_bf16(bh, al[kc], acc, 0, 0, 0);
      }
      float4 s4 = *(const float4*)(sq + (size_t)b * NN + m0 + tt * 16 + quad * 4);
      const float sv[4] = {s4.x, s4.y, s4.z, s4.w};
      #pragma unroll
      for (int r = 0; r < 4; ++r) {
        float v = fmaf(2.f, acc[r], -sr) - sv[r];
        unsigned int key = fmono(v);
        if (key >= theta) {
          int col = m0 + tt * 16 + quad * 4 + r;
          uint64_t item = ((uint64_t)key << 32) | (unsigned int)~col;
          if (key > theta) {
            if (cntg + cntt == KNN && cntt > 0) --cntt;  // evict largest-col theta
            if (cntg < KNN) myslots[cntg++] = item;
          } else if (cntg + cntt < KNN) {
            myslots[(KNN - 1) - cntt] = item;            // back-fill, asc col
            ++cntt;
          }
        }
      }
    }
  }
  __syncthreads();

  if (t < TILE) {
    uint64_t fk[KNN];
    #pragma unroll
    for (int j = 0; j < KNN; ++j) fk[j] = 0ull;
    uint64_t m2 = 0ull; int m2s = 0;
    for (int qq = 0; qq < 4; ++qq)
      #pragma unroll
      for (int j = 0; j < KNN; ++j)
        topk_u64(sk[((size_t)t * 4 + qq) * KNN + j], fk, m2, m2s);
    size_t base = (((size_t)b * NCH + chunk) * NN + r0 + t) * KNN;
    #pragma unroll
    for (int j = 0; j < KNN; ++j) cand_k[base + j] = fk[j];
  }
}

// ---------------------------------------------------------------------------
// K5: chunk-merge (fused) + gather + grouped conv + bn + relu + max over K.
// ---------------------------------------------------------------------------
__global__ __launch_bounds__(256) void k_gconv(const float* __restrict__ y1t,
                                               const uint64_t* __restrict__ cand_k,
                                               const float* __restrict__ gw,
                                               const float* __restrict__ gb,
                                               const float* __restrict__ bng,
                                               float* __restrict__ ymax) {
  __shared__ float wl[C2 * 48];
  __shared__ float xi[PT * CC];
  __shared__ float fj[PT * CC * 12];
  __shared__ int idxl[PT * KNN];
  const int t = threadIdx.x;
  const int p0 = blockIdx.x * PT;      // NN%PT==0 -> block never straddles batch
  const int b0 = p0 / NN, n00 = p0 % NN;

  for (int i = t; i < C2 * 48 / 4; i += 256) ((float4*)wl)[i] = ((const float4*)gw)[i];
  for (int i = t; i < PT * CC; i += 256) xi[i] = y1t[(size_t)p0 * CC + i];
  if (t < PT) {  // fused chunk-merge: 8 chunk lists -> top-9 for position p0+t
    uint64_t fk[KNN];
    #pragma unroll
    for (int j = 0; j < KNN; ++j) fk[j] = 0ull;
    uint64_t mnk = 0ull; int mns = 0;
    for (int ch = 0; ch < NCH; ++ch) {
      size_t base = (((size_t)b0 * NCH + ch) * NN + n00 + t) * KNN;
      #pragma unroll
      for (int j = 0; j < KNN; ++j) topk_u64(cand_k[base + j], fk, mnk, mns);
    }
    #pragma unroll
    for (int j = 0; j < KNN; ++j) {
      int v = (int)(~(unsigned int)fk[j]);
      idxl[t * KNN + j] = ((unsigned)v < (unsigned)NN) ? v : 0;
    }
  }
  __syncthreads();

  for (int i = t; i < PT * KNN * CC; i += 256) {
    int pk = i / CC, c = i % CC;
    int p = pk / KNN, k = pk % KNN;
    int j = idxl[p * KNN + k];
    float v = y1t[((size_t)b0 * NN + j) * CC + c] - xi[p * CC + c];
    fj[(p * CC + c) * 12 + k] = v;
  }
  __syncthreads();

  const int p = t >> 5, l = t & 31;
  float* orow = ymax + ((size_t)p0 + p) * C2;
  const float* xip = xi + p * CC;
  const float* fp = fj + (size_t)p * CC * 12;

  auto bnrelu = [&](int oc, float a) -> float {
    float g = bng[oc], be = bng[C2 + oc], mn = bng[2 * C2 + oc], vr = bng[3 * C2 + oc];
    float inv = g / sqrtf(vr + 1e-5f);
    return fmaxf(fmaf(a + gb[oc], inv, be - mn * inv), 0.f);
  };

  {  // k-free half: oc = l, l+32, l+64  (float4 over c)
    const int oc0 = l, oc1 = l + 32, oc2 = l + 64;
    const int cb0 = (oc0 / 48) * 48, cb1 = (oc1 / 48) * 48, cb2 = (oc2 / 48) * 48;
    float a0 = 0.f, a1 = 0.f, a2 = 0.f;
    #pragma unroll 4
    for (int c = 0; c < 48; c += 4) {
      float4 w0 = *(const float4*)&wl[oc0 * 48 + c];
      float4 w1 = *(const float4*)&wl[oc1 * 48 + c];
      float4 w2 = *(const float4*)&wl[oc2 * 48 + c];
      float4 x0 = *(const float4*)&xip[cb0 + c];
      float4 x1 = *(const float4*)&xip[cb1 + c];
      float4 x2 = *(const float4*)&xip[cb2 + c];
      a0 += w0.x * x0.x + w0.y * x0.y + w0.z * x0.z + w0.w * x0.w;
      a1 += w1.x * x1.x + w1.y * x1.y + w1.z * x1.z + w1.w * x1.w;
      a2 += w2.x * x2.x + w2.y * x2.y + w2.z * x2.z + w2.w * x2.w;
    }
    orow[oc0] = bnrelu(oc0, a0);
    orow[oc1] = bnrelu(oc1, a1);
    orow[oc2] = bnrelu(oc2, a2);
  }
  {  // k-dependent half: oc = 96+l, 128+l, 160+l; fj read as 2xfloat4 + 1
    const int oc0 = 96 + l, oc1 = 128 + l, oc2 = 160 + l;
    const int db0 = ((oc0 - 96) / 48) * 48, db1 = ((oc1 - 96) / 48) * 48,
              db2 = ((oc2 - 96) / 48) * 48;
    float acc0[KNN], acc1[KNN], acc2[KNN];
    #pragma unroll
    for (int k = 0; k < KNN; ++k) { acc0[k] = 0.f; acc1[k] = 0.f; acc2[k] = 0.f; }
    #pragma unroll 2
    for (int c = 0; c < 48; ++c) {
      float w0 = wl[oc0 * 48 + c], w1 = wl[oc1 * 48 + c], w2 = wl[oc2 * 48 + c];
      const float* f0 = fp + (db0 + c) * 12;
      const float* f1 = fp + (db1 + c) * 12;
      const float* f2 = fp + (db2 + c) * 12;
      float4 f0a = *(const float4*)f0, f0b = *(const float4*)(f0 + 4);
      float4 f1a = *(const float4*)f1, f1b = *(const float4*)(f1 + 4);
      float4 f2a = *(const float4*)f2, f2b = *(const float4*)(f2 + 4);
      float f08 = f0[8], f18 = f1[8], f28 = f2[8];
      acc0[0] = fmaf(w0, f0a.x, acc0[0]); acc0[1] = fmaf(w0, f0a.y, acc0[1]);
      acc0[2] = fmaf(w0, f0a.z, acc0[2]); acc0[3] = fmaf(w0, f0a.w, acc0[3]);
      acc0[4] = fmaf(w0, f0b.x, acc0[4]); acc0[5] = fmaf(w0, f0b.y, acc0[5]);
      acc0[6] = fmaf(w0, f0b.z, acc0[6]); acc0[7] = fmaf(w0, f0b.w, acc0[7]);
      acc0[8] = fmaf(w0, f08, acc0[8]);
      acc1[0] = fmaf(w1, f1a.x, acc1[0]); acc1[1] = fmaf(w1, f1a.y, acc1[1]);
      acc1[2] = fmaf(w1, f1a.z, acc1[2]); acc1[3] = fmaf(w1, f1a.w, acc1[3]);
      acc1[4] = fmaf(w1, f1b.x, acc1[4]); acc1[5] = fmaf(w1, f1b.y, acc1[5]);
      acc1[6] = fmaf(w1, f1b.z, acc1[6]); acc1[7] = fmaf(w1, f1b.w, acc1[7]);
      acc1[8] = fmaf(w1, f18, acc1[8]);
      acc2[0] = fmaf(w2, f2a.x, acc2[0]); acc2[1] = fmaf(w2, f2a.y, acc2[1]);
      acc2[2] = fmaf(w2, f2a.z, acc2[2]); acc2[3] = fmaf(w2, f2a.w, acc2[3]);
      acc2[4] = fmaf(w2, f2b.x, acc2[4]); acc2[5] = fmaf(w2, f2b.y, acc2[5]);
      acc2[6] = fmaf(w2, f2b.z, acc2[6]); acc2[7] = fmaf(w2, f2b.w, acc2[7]);
      acc2[8] = fmaf(w2, f28, acc2[8]);
    }
    #pragma unroll
    for (int oo = 0; oo < 3; ++oo) {
      int oc = (oo == 0) ? oc0 : (oo == 1) ? oc1 : oc2;
      const float* ac = (oo == 0) ? acc0 : (oo == 1) ? acc1 : acc2;
      float g = bng[oc], be = bng[C2 + oc], mn = bng[2 * C2 + oc], vr = bng[3 * C2 + oc];
      float inv = g / sqrtf(vr + 1e-5f), sh = be - mn * inv, bs = gb[oc], m = 0.f;
      #pragma unroll
      for (int k = 0; k < KNN; ++k) m = fmaxf(m, fmaxf(fmaf(ac[k] + bs, inv, sh), 0.f));
      orow[oc] = m;
    }
  }
}

// ---------------------------------------------------------------------------
// K6: out = bn2(fc2_w @ ymax + fc2_b) + x
// ---------------------------------------------------------------------------
__global__ __launch_bounds__(256) void k_fc2(const float* __restrict__ ymax,
                                             const float* __restrict__ w2,
                                             const float* __restrict__ b2,
                                             const float* __restrict__ bn2,
                                             const float* __restrict__ xin,
                                             float* __restrict__ out) {
  __shared__ float ys[64 * 193];
  const int b = blockIdx.y, n0 = blockIdx.x * 64, t = threadIdx.x;
  for (int i = t; i < 64 * C2; i += 256) {
    int nn = i / C2, c2 = i % C2;
    ys[nn * 193 + c2] = ymax[((size_t)b * NN + n0 + nn) * C2 + c2];
  }
  __syncthreads();
  const int nn = t & 63;
  const int og = __builtin_amdgcn_readfirstlane(t >> 6);
  float acc[24];
  #pragma unroll
  for (int i = 0; i < 24; ++i) acc[i] = 0.f;
  const float* yrow = ys + nn * 193;
  for (int c2 = 0; c2 < C2; ++c2) {
    float yv = yrow[c2];
    const float* wp = w2 + (size_t)(og * 24) * C2 + c2;
    #pragma unroll
    for (int oi = 0; oi < 24; ++oi) acc[oi] = fmaf(wp[oi * C2], yv, acc[oi]);
  }
  #pragma unroll
  for (int oi = 0; oi < 24; ++oi) {
    int o = og * 24 + oi;
    float g = bn2[o], be = bn2[CC + o], mn = bn2[2 * CC + o], vr = bn2[3 * CC + o];
    float inv = g / sqrtf(vr + 1e-5f);
    float v = fmaf(acc[oi] + b2[o], inv, be - mn * inv);
    size_t off = ((size_t)b * CC + o) * NN + n0 + nn;
    out[off] = v + xin[off];
  }
}

// ---------------------------------------------------------------------------
extern "C" void kernel_launch(void* const* d_in, const int* in_sizes, int n_in,
                              void* d_out, int out_size, void* d_ws, size_t ws_size,
                              hipStream_t stream) {
  const float* x     = (const float*)d_in[0];
  const float* fc1_w = (const float*)d_in[1];
  const float* fc1_b = (const float*)d_in[2];
  const float* bn1   = (const float*)d_in[3];
  const float* gc_w  = (const float*)d_in[4];
  const float* gc_b  = (const float*)d_in[5];
  const float* bng   = (const float*)d_in[6];
  const float* fc2_w = (const float*)d_in[7];
  const float* fc2_b = (const float*)d_in[8];
  const float* bn2   = (const float*)d_in[9];
  float* out = (float*)d_out;

  const size_t BNC = (size_t)BN_ * NN * CC;
  float* ws = (float*)d_ws;
  float* y1t = ws;                                   // B*N*C fp32
  unsigned short* xh = (unsigned short*)(y1t + BNC); // B*N*C bf16 hi
  unsigned short* xl = xh + BNC;                     // B*N*C bf16 lo
  float* sq     = ws + 2 * BNC;                      // B*N
  float* ymax   = sq + (size_t)BN_ * NN;             // B*N*C2
  uint64_t* cand_k = (uint64_t*)(ymax + (size_t)BN_ * NN * C2);  // B*NCH*N*9 u64

  k_fc1<<<dim3(NN / 64, BN_), 256, 0, stream>>>(x, fc1_w, fc1_b, bn1, y1t);
  k_norm<<<dim3((BN_ * NN) / 256), 256, 0, stream>>>(y1t, xh, xl, sq);
  k_dist<<<dim3(NN / TILE, NCH, BN_), 256, 0, stream>>>(xh, xl, sq, cand_k);
  k_gconv<<<dim3((BN_ * NN) / PT), 256, 0, stream>>>(y1t, cand_k, gc_w, gc_b, bng, ymax);
  k_fc2<<<dim3(NN / 64, BN_), 256, 0, stream>>>(ymax, fc2_w, fc2_b, bn2, x, out);
}

// Round 8
// 423.352 us; speedup vs baseline: 1.0397x; 1.0397x over previous
//
#include <hip/hip_runtime.h>
#include <cstdint>
#include <cstddef>

#define BN_   4
#define CC    96
#define C2    192
#define NN    3136
#define KNN   9
#define TILE  64
#define PT    8
#define NCH   8   // column chunks for k_dist

typedef __attribute__((ext_vector_type(8))) __bf16 bf16x8;
typedef __attribute__((ext_vector_type(4))) float f32x4;

__device__ __forceinline__ unsigned short f2bf(float f) {
  unsigned int u = __float_as_uint(f);
  unsigned int r = u + 0x7fffu + ((u >> 16) & 1u);   // RNE
  return (unsigned short)(r >> 16);
}
__device__ __forceinline__ float bf2f(unsigned short h) {
  return __uint_as_float(((unsigned int)h) << 16);
}
// monotone map: fmono(a) > fmono(b)  <=>  a > b  (as floats)
__device__ __forceinline__ unsigned int fmono(float f) {
  unsigned int s = __float_as_uint(f);
  return s ^ ((unsigned int)((int)s >> 31) | 0x80000000u);
}
// branchless sorted-ascending top-9 insert: ~17 v_min/v_max_u32, no branches
__device__ __forceinline__ void chain9(unsigned int key, unsigned int (&bv)[KNN]) {
  unsigned int c = key > bv[0] ? key : bv[0];
  #pragma unroll
  for (int j = 1; j < KNN; ++j) {
    unsigned int lo = c < bv[j] ? c : bv[j];
    unsigned int hi = c < bv[j] ? bv[j] : c;
    bv[j - 1] = lo; c = hi;
  }
  bv[KNN - 1] = c;
}
// u64 (key<<32 | ~col) top-9, unordered + cached min (branchy; small streams)
__device__ __forceinline__ void topk_u64(uint64_t key, uint64_t (&bk)[KNN],
                                         uint64_t& mnk, int& mns) {
  if (key > mnk) {
    #pragma unroll
    for (int j = 0; j < KNN; ++j) if (j == mns) bk[j] = key;
    mnk = bk[0]; mns = 0;
    #pragma unroll
    for (int j = 1; j < KNN; ++j) if (bk[j] < mnk) { mnk = bk[j]; mns = j; }
  }
}

// ---------------------------------------------------------------------------
// K1: y1t[b][n][o] = bn1(fc1_w @ x + fc1_b).  BIT-EXACT R4 version.
// DO NOT change the arithmetic/order here: xh/xl/sq feed a discrete top-k;
// any ulp change can flip a neighbor (verified: R5/R6 fused-norm failure).
// ---------------------------------------------------------------------------
__global__ __launch_bounds__(256) void k_fc1(const float* __restrict__ x,
                                             const float* __restrict__ w,
                                             const float* __restrict__ bias,
                                             const float* __restrict__ bn,
                                             float* __restrict__ y1t) {
  __shared__ float xs[CC * 64];  // [c][64]
  const int b = blockIdx.y, n0 = blockIdx.x * 64;
  const int t = threadIdx.x;
  for (int i = t; i < CC * 64; i += 256) {
    int c = i >> 6, nn = i & 63;
    xs[i] = x[((size_t)b * CC + c) * NN + n0 + nn];
  }
  __syncthreads();
  const int nn = t & 63;
  const int og = __builtin_amdgcn_readfirstlane(t >> 6);
  float acc[24];
  #pragma unroll
  for (int i = 0; i < 24; ++i) acc[i] = 0.f;
  for (int c = 0; c < CC; ++c) {
    float xv = xs[c * 64 + nn];
    const float* wp = w + (size_t)(og * 24) * CC + c;
    #pragma unroll
    for (int oi = 0; oi < 24; ++oi) acc[oi] = fmaf(wp[oi * CC], xv, acc[oi]);
  }
  #pragma unroll
  for (int oi = 0; oi < 24; ++oi) {
    int o = og * 24 + oi;
    float g = bn[o], be = bn[CC + o], mn = bn[2 * CC + o], vr = bn[3 * CC + o];
    float inv = g / sqrtf(vr + 1e-5f);
    float v = fmaf(acc[oi] + bias[o], inv, be - mn * inv);
    y1t[((size_t)b * NN + n0 + nn) * CC + o] = v;
  }
}

// ---------------------------------------------------------------------------
// K2: per-position L2 norm; bf16 split (hi, lo) + sq.  BIT-EXACT R4 version.
// ---------------------------------------------------------------------------
__global__ __launch_bounds__(256) void k_norm(const float* __restrict__ y1t,
                                              unsigned short* __restrict__ xh,
                                              unsigned short* __restrict__ xl,
                                              float* __restrict__ sq) {
  const int p = blockIdx.x * 256 + threadIdx.x;  // 49*256 == 12544 exactly
  const float* row = y1t + (size_t)p * CC;
  float s = 0.f;
  for (int c = 0; c < CC; c += 4) {
    float4 v = *(const float4*)(row + c);
    s += v.x * v.x; s += v.y * v.y; s += v.z * v.z; s += v.w * v.w;
  }
  float inv = 1.f / fmaxf(sqrtf(s), 1e-12f);
  float sqs = 0.f;
  unsigned short* hrow = xh + (size_t)p * CC;
  unsigned short* lrow = xl + (size_t)p * CC;
  for (int c = 0; c < CC; ++c) {
    float v = row[c] * inv;
    sqs += v * v;
    unsigned short h = f2bf(v);
    float lo = v - bf2f(h);
    hrow[c] = h;
    lrow[c] = f2bf(lo);
  }
  sq[p] = sqs;
}

// ---------------------------------------------------------------------------
// K3: two-pass kNN (unchanged from R7 — passing).
// ---------------------------------------------------------------------------
__global__ __launch_bounds__(256) void k_dist(const unsigned short* __restrict__ xh,
                                              const unsigned short* __restrict__ xl,
                                              const float* __restrict__ sq,
                                              uint64_t* __restrict__ cand_k) {
  __shared__ __align__(16) unsigned short sB[2 * 64 * 104];  // 26624 B
  __shared__ __align__(16) float sqm[TILE];
  unsigned short* BsH = sB;
  unsigned short* BsL = sB + 64 * 104;
  uint64_t* sk = (uint64_t*)sB;   // pass-2 hit slots alias sB (dead then)

  const int rt = blockIdx.x, chunk = blockIdx.y, b = blockIdx.z;
  const int r0 = rt * TILE;
  const int t = threadIdx.x;
  const int lane = t & 63, w = t >> 6;
  const int m16 = lane & 15, quad = lane >> 4;
  const int mt0 = (49 * chunk) / NCH, mt1 = (49 * (chunk + 1)) / NCH;

  const int gr = r0 + w * 16 + m16;
  bf16x8 ah[3], al[3];
  {
    const unsigned short* pH = xh + ((size_t)b * NN + gr) * CC + quad * 8;
    const unsigned short* pL = xl + ((size_t)b * NN + gr) * CC + quad * 8;
    #pragma unroll
    for (int kc = 0; kc < 3; ++kc) {
      ah[kc] = *(const bf16x8*)(pH + kc * 32);
      al[kc] = *(const bf16x8*)(pL + kc * 32);
    }
  }
  const float sr = sq[b * NN + gr];

  unsigned int bv[KNN];
  #pragma unroll
  for (int j = 0; j < KNN; ++j) bv[j] = 0u;

  // ---- pass 1 ----
  const int srow_ = t >> 2, sch = t & 3;   // pow2 staging map
  for (int mt = mt0; mt < mt1; ++mt) {
    const int m0 = mt * TILE;
    __syncthreads();
    {
      const size_t rbase = ((size_t)b * NN + m0 + srow_) * CC;
      #pragma unroll
      for (int it = 0; it < 3; ++it) {
        int ch = sch + (it << 2);
        *(uint4*)&BsH[srow_ * 104 + ch * 8] = *(const uint4*)(xh + rbase + ch * 8);
        *(uint4*)&BsL[srow_ * 104 + ch * 8] = *(const uint4*)(xl + rbase + ch * 8);
      }
    }
    if (t < TILE) sqm[t] = sq[b * NN + m0 + t];
    __syncthreads();

    #pragma unroll
    for (int tt = 0; tt < 4; ++tt) {
      const int brow = (tt * 16 + m16) * 104 + quad * 8;
      f32x4 acc = {0.f, 0.f, 0.f, 0.f};
      #pragma unroll
      for (int kc = 0; kc < 3; ++kc) {
        bf16x8 bh = *(const bf16x8*)&BsH[brow + kc * 32];
        bf16x8 bl = *(const bf16x8*)&BsL[brow + kc * 32];
        acc = __builtin_amdgcn_mfma_f32_16x16x32_bf16(bh, ah[kc], acc, 0, 0, 0);
        acc = __builtin_amdgcn_mfma_f32_16x16x32_bf16(bl, ah[kc], acc, 0, 0, 0);
        acc = __builtin_amdgcn_mfma_f32_16x16x32_bf16(bh, al[kc], acc, 0, 0, 0);
      }
      float4 s4 = *(const float4*)&sqm[tt * 16 + quad * 4];
      const float sv[4] = {s4.x, s4.y, s4.z, s4.w};
      #pragma unroll
      for (int r = 0; r < 4; ++r) {
        float v = fmaf(2.f, acc[r], -sr) - sv[r];
        chain9(fmono(v), bv);
      }
    }
  }
  __syncthreads();   // all pass-1 LDS reads done before sk aliases sB

  // ---- pass 2 ----
  const unsigned int theta = bv[0];
  uint64_t* myslots = sk + ((size_t)(w * 16 + m16) * 4 + quad) * KNN;
  #pragma unroll
  for (int j = 0; j < KNN; ++j) myslots[j] = 0ull;
  int cntg = 0, cntt = 0;
  for (int mt = mt0; mt < mt1; ++mt) {
    const int m0 = mt * TILE;
    #pragma unroll
    for (int tt = 0; tt < 4; ++tt) {
      const size_t brbase = ((size_t)b * NN + m0 + tt * 16 + m16) * CC + quad * 8;
      f32x4 acc = {0.f, 0.f, 0.f, 0.f};
      #pragma unroll
      for (int kc = 0; kc < 3; ++kc) {
        bf16x8 bh = *(const bf16x8*)(xh + brbase + kc * 32);
        bf16x8 bl = *(const bf16x8*)(xl + brbase + kc * 32);
        acc = __builtin_amdgcn_mfma_f32_16x16x32_bf16(bh, ah[kc], acc, 0, 0, 0);
        acc = __builtin_amdgcn_mfma_f32_16x16x32_bf16(bl, ah[kc], acc, 0, 0, 0);
        acc = __builtin_amdgcn_mfma_f32_16x16x32_bf16(bh, al[kc], acc, 0, 0, 0);
      }
      float4 s4 = *(const float4*)(sq + (size_t)b * NN + m0 + tt * 16 + quad * 4);
      const float sv[4] = {s4.x, s4.y, s4.z, s4.w};
      #pragma unroll
      for (int r = 0; r < 4; ++r) {
        float v = fmaf(2.f, acc[r], -sr) - sv[r];
        unsigned int key = fmono(v);
        if (key >= theta) {
          int col = m0 + tt * 16 + quad * 4 + r;
          uint64_t item = ((uint64_t)key << 32) | (unsigned int)~col;
          if (key > theta) {
            if (cntg + cntt == KNN && cntt > 0) --cntt;  // evict largest-col theta
            if (cntg < KNN) myslots[cntg++] = item;
          } else if (cntg + cntt < KNN) {
            myslots[(KNN - 1) - cntt] = item;            // back-fill, asc col
            ++cntt;
          }
        }
      }
    }
  }
  __syncthreads();

  if (t < TILE) {
    uint64_t fk[KNN];
    #pragma unroll
    for (int j = 0; j < KNN; ++j) fk[j] = 0ull;
    uint64_t m2 = 0ull; int m2s = 0;
    for (int qq = 0; qq < 4; ++qq)
      #pragma unroll
      for (int j = 0; j < KNN; ++j)
        topk_u64(sk[((size_t)t * 4 + qq) * KNN + j], fk, m2, m2s);
    size_t base = (((size_t)b * NCH + chunk) * NN + r0 + t) * KNN;
    #pragma unroll
    for (int j = 0; j < KNN; ++j) cand_k[base + j] = fk[j];
  }
}

// ---------------------------------------------------------------------------
// K5: chunk-merge + gather + grouped conv + bn + relu + max over K.
// R8 change: weight tile layout wl[c*193 + oc].  bank = (c + oc) % 32:
//   - compute reads (c uniform, oc = base+lane) -> 32 distinct banks, free
//   - staging writes (oc uniform per run, c = f(lane)) -> distinct banks, free
// R5..R7 used stride 48 (48 = 16 mod 32) -> every weight read was a 16-way
// conflict (SQ_LDS_BANK_CONFLICT 2e7, 183 us).  // DO NOT use pow2 stride.
// ---------------------------------------------------------------------------
__global__ __launch_bounds__(256) void k_gconv(const float* __restrict__ y1t,
                                               const uint64_t* __restrict__ cand_k,
                                               const float* __restrict__ gw,
                                               const float* __restrict__ gb,
                                               const float* __restrict__ bng,
                                               float* __restrict__ ymax) {
  __shared__ float wl[48 * 193];       // [c][oc], stride 193
  __shared__ float xi[PT * CC];
  __shared__ float fj[PT * CC * 12];
  __shared__ int idxl[PT * KNN];
  const int t = threadIdx.x;
  const int p0 = blockIdx.x * PT;      // NN%PT==0 -> block never straddles batch
  const int b0 = p0 / NN, n00 = p0 % NN;

  for (int i = t; i < C2 * 48; i += 256) {
    int oc = i / 48, c = i % 48;       // gw read coalesced; wl write conflict-free
    wl[c * 193 + oc] = gw[i];
  }
  for (int i = t; i < PT * CC; i += 256) xi[i] = y1t[(size_t)p0 * CC + i];
  if (t < PT) {  // fused chunk-merge: 8 chunk lists -> top-9 for position p0+t
    uint64_t fk[KNN];
    #pragma unroll
    for (int j = 0; j < KNN; ++j) fk[j] = 0ull;
    uint64_t mnk = 0ull; int mns = 0;
    for (int ch = 0; ch < NCH; ++ch) {
      size_t base = (((size_t)b0 * NCH + ch) * NN + n00 + t) * KNN;
      #pragma unroll
      for (int j = 0; j < KNN; ++j) topk_u64(cand_k[base + j], fk, mnk, mns);
    }
    #pragma unroll
    for (int j = 0; j < KNN; ++j) {
      int v = (int)(~(unsigned int)fk[j]);
      idxl[t * KNN + j] = ((unsigned)v < (unsigned)NN) ? v : 0;
    }
  }
  __syncthreads();

  for (int i = t; i < PT * KNN * CC; i += 256) {
    int pk = i / CC, c = i % CC;
    int p = pk / KNN, k = pk % KNN;
    int j = idxl[p * KNN + k];
    float v = y1t[((size_t)b0 * NN + j) * CC + c] - xi[p * CC + c];
    fj[(p * CC + c) * 12 + k] = v;
  }
  __syncthreads();

  const int p = t >> 5, l = t & 31;
  float* orow = ymax + ((size_t)p0 + p) * C2;
  const float* xip = xi + p * CC;
  const float* fp = fj + (size_t)p * CC * 12;

  auto bnrelu = [&](int oc, float a) -> float {
    float g = bng[oc], be = bng[C2 + oc], mn = bng[2 * C2 + oc], vr = bng[3 * C2 + oc];
    float inv = g / sqrtf(vr + 1e-5f);
    return fmaxf(fmaf(a + gb[oc], inv, be - mn * inv), 0.f);
  };

  {  // k-free half: oc = l, l+32, l+64 (scalar, conflict-free banks)
    const int oc0 = l, oc1 = l + 32, oc2 = l + 64;
    const int cb0 = (oc0 / 48) * 48, cb1 = (oc1 / 48) * 48, cb2 = (oc2 / 48) * 48;
    float a0 = 0.f, a1 = 0.f, a2 = 0.f;
    #pragma unroll 8
    for (int c = 0; c < 48; ++c) {
      const float* wrow = wl + c * 193;
      a0 = fmaf(wrow[oc0], xip[cb0 + c], a0);
      a1 = fmaf(wrow[oc1], xip[cb1 + c], a1);
      a2 = fmaf(wrow[oc2], xip[cb2 + c], a2);
    }
    orow[oc0] = bnrelu(oc0, a0);
    orow[oc1] = bnrelu(oc1, a1);
    orow[oc2] = bnrelu(oc2, a2);
  }
  {  // k-dependent half: oc = 96+l, 128+l, 160+l; fj read as 2xfloat4 + 1
    const int oc0 = 96 + l, oc1 = 128 + l, oc2 = 160 + l;
    const int db0 = ((oc0 - 96) / 48) * 48, db1 = ((oc1 - 96) / 48) * 48,
              db2 = ((oc2 - 96) / 48) * 48;
    float acc0[KNN], acc1[KNN], acc2[KNN];
    #pragma unroll
    for (int k = 0; k < KNN; ++k) { acc0[k] = 0.f; acc1[k] = 0.f; acc2[k] = 0.f; }
    #pragma unroll 2
    for (int c = 0; c < 48; ++c) {
      const float* wrow = wl + c * 193;
      float w0 = wrow[oc0], w1 = wrow[oc1], w2 = wrow[oc2];
      const float* f0 = fp + (db0 + c) * 12;
      const float* f1 = fp + (db1 + c) * 12;
      const float* f2 = fp + (db2 + c) * 12;
      float4 f0a = *(const float4*)f0, f0b = *(const float4*)(f0 + 4);
      float4 f1a = *(const float4*)f1, f1b = *(const float4*)(f1 + 4);
      float4 f2a = *(const float4*)f2, f2b = *(const float4*)(f2 + 4);
      float f08 = f0[8], f18 = f1[8], f28 = f2[8];
      acc0[0] = fmaf(w0, f0a.x, acc0[0]); acc0[1] = fmaf(w0, f0a.y, acc0[1]);
      acc0[2] = fmaf(w0, f0a.z, acc0[2]); acc0[3] = fmaf(w0, f0a.w, acc0[3]);
      acc0[4] = fmaf(w0, f0b.x, acc0[4]); acc0[5] = fmaf(w0, f0b.y, acc0[5]);
      acc0[6] = fmaf(w0, f0b.z, acc0[6]); acc0[7] = fmaf(w0, f0b.w, acc0[7]);
      acc0[8] = fmaf(w0, f08, acc0[8]);
      acc1[0] = fmaf(w1, f1a.x, acc1[0]); acc1[1] = fmaf(w1, f1a.y, acc1[1]);
      acc1[2] = fmaf(w1, f1a.z, acc1[2]); acc1[3] = fmaf(w1, f1a.w, acc1[3]);
      acc1[4] = fmaf(w1, f1b.x, acc1[4]); acc1[5] = fmaf(w1, f1b.y, acc1[5]);
      acc1[6] = fmaf(w1, f1b.z, acc1[6]); acc1[7] = fmaf(w1, f1b.w, acc1[7]);
      acc1[8] = fmaf(w1, f18, acc1[8]);
      acc2[0] = fmaf(w2, f2a.x, acc2[0]); acc2[1] = fmaf(w2, f2a.y, acc2[1]);
      acc2[2] = fmaf(w2, f2a.z, acc2[2]); acc2[3] = fmaf(w2, f2a.w, acc2[3]);
      acc2[4] = fmaf(w2, f2b.x, acc2[4]); acc2[5] = fmaf(w2, f2b.y, acc2[5]);
      acc2[6] = fmaf(w2, f2b.z, acc2[6]); acc2[7] = fmaf(w2, f2b.w, acc2[7]);
      acc2[8] = fmaf(w2, f28, acc2[8]);
    }
    #pragma unroll
    for (int oo = 0; oo < 3; ++oo) {
      int oc = (oo == 0) ? oc0 : (oo == 1) ? oc1 : oc2;
      const float* ac = (oo == 0) ? acc0 : (oo == 1) ? acc1 : acc2;
      float g = bng[oc], be = bng[C2 + oc], mn = bng[2 * C2 + oc], vr = bng[3 * C2 + oc];
      float inv = g / sqrtf(vr + 1e-5f), sh = be - mn * inv, bs = gb[oc], m = 0.f;
      #pragma unroll
      for (int k = 0; k < KNN; ++k) m = fmaxf(m, fmaxf(fmaf(ac[k] + bs, inv, sh), 0.f));
      orow[oc] = m;
    }
  }
}

// ---------------------------------------------------------------------------
// K6: out = bn2(fc2_w @ ymax + fc2_b) + x
// ---------------------------------------------------------------------------
__global__ __launch_bounds__(256) void k_fc2(const float* __restrict__ ymax,
                                             const float* __restrict__ w2,
                                             const float* __restrict__ b2,
                                             const float* __restrict__ bn2,
                                             const float* __restrict__ xin,
                                             float* __restrict__ out) {
  __shared__ float ys[64 * 193];
  const int b = blockIdx.y, n0 = blockIdx.x * 64, t = threadIdx.x;
  for (int i = t; i < 64 * C2; i += 256) {
    int nn = i / C2, c2 = i % C2;
    ys[nn * 193 + c2] = ymax[((size_t)b * NN + n0 + nn) * C2 + c2];
  }
  __syncthreads();
  const int nn = t & 63;
  const int og = __builtin_amdgcn_readfirstlane(t >> 6);
  float acc[24];
  #pragma unroll
  for (int i = 0; i < 24; ++i) acc[i] = 0.f;
  const float* yrow = ys + nn * 193;
  for (int c2 = 0; c2 < C2; ++c2) {
    float yv = yrow[c2];
    const float* wp = w2 + (size_t)(og * 24) * C2 + c2;
    #pragma unroll
    for (int oi = 0; oi < 24; ++oi) acc[oi] = fmaf(wp[oi * C2], yv, acc[oi]);
  }
  #pragma unroll
  for (int oi = 0; oi < 24; ++oi) {
    int o = og * 24 + oi;
    float g = bn2[o], be = bn2[CC + o], mn = bn2[2 * CC + o], vr = bn2[3 * CC + o];
    float inv = g / sqrtf(vr + 1e-5f);
    float v = fmaf(acc[oi] + b2[o], inv, be - mn * inv);
    size_t off = ((size_t)b * CC + o) * NN + n0 + nn;
    out[off] = v + xin[off];
  }
}

// ---------------------------------------------------------------------------
extern "C" void kernel_launch(void* const* d_in, const int* in_sizes, int n_in,
                              void* d_out, int out_size, void* d_ws, size_t ws_size,
                              hipStream_t stream) {
  const float* x     = (const float*)d_in[0];
  const float* fc1_w = (const float*)d_in[1];
  const float* fc1_b = (const float*)d_in[2];
  const float* bn1   = (const float*)d_in[3];
  const float* gc_w  = (const float*)d_in[4];
  const float* gc_b  = (const float*)d_in[5];
  const float* bng   = (const float*)d_in[6];
  const float* fc2_w = (const float*)d_in[7];
  const float* fc2_b = (const float*)d_in[8];
  const float* bn2   = (const float*)d_in[9];
  float* out = (float*)d_out;

  const size_t BNC = (size_t)BN_ * NN * CC;
  float* ws = (float*)d_ws;
  float* y1t = ws;                                   // B*N*C fp32
  unsigned short* xh = (unsigned short*)(y1t + BNC); // B*N*C bf16 hi
  unsigned short* xl = xh + BNC;                     // B*N*C bf16 lo
  float* sq     = ws + 2 * BNC;                      // B*N
  float* ymax   = sq + (size_t)BN_ * NN;             // B*N*C2
  uint64_t* cand_k = (uint64_t*)(ymax + (size_t)BN_ * NN * C2);  // B*NCH*N*9 u64

  k_fc1<<<dim3(NN / 64, BN_), 256, 0, stream>>>(x, fc1_w, fc1_b, bn1, y1t);
  k_norm<<<dim3((BN_ * NN) / 256), 256, 0, stream>>>(y1t, xh, xl, sq);
  k_dist<<<dim3(NN / TILE, NCH, BN_), 256, 0, stream>>>(xh, xl, sq, cand_k);
  k_gconv<<<dim3((BN_ * NN) / PT), 256, 0, stream>>>(y1t, cand_k, gc_w, gc_b, bng, ymax);
  k_fc2<<<dim3(NN / 64, BN_), 256, 0, stream>>>(ymax, fc2_w, fc2_b, bn2, x, out);
}

// Round 9
// 371.020 us; speedup vs baseline: 1.1863x; 1.1410x over previous
//
#include <hip/hip_runtime.h>
#include <cstdint>
#include <cstddef>

#define BN_   4
#define CC    96
#define C2    192
#define NN    3136
#define KNN   9
#define TILE  64
#define PT    8
#define NCH   8   // column chunks for k_dist

typedef __attribute__((ext_vector_type(8))) __bf16 bf16x8;
typedef __attribute__((ext_vector_type(4))) float f32x4;

__device__ __forceinline__ unsigned short f2bf(float f) {
  unsigned int u = __float_as_uint(f);
  unsigned int r = u + 0x7fffu + ((u >> 16) & 1u);   // RNE
  return (unsigned short)(r >> 16);
}
__device__ __forceinline__ float bf2f(unsigned short h) {
  return __uint_as_float(((unsigned int)h) << 16);
}
// monotone map: fmono(a) > fmono(b)  <=>  a > b  (as floats)
__device__ __forceinline__ unsigned int fmono(float f) {
  unsigned int s = __float_as_uint(f);
  return s ^ ((unsigned int)((int)s >> 31) | 0x80000000u);
}
// branchless sorted-ascending top-9 insert: ~17 v_min/v_max_u32, no branches
__device__ __forceinline__ void chain9(unsigned int key, unsigned int (&bv)[KNN]) {
  unsigned int c = key > bv[0] ? key : bv[0];
  #pragma unroll
  for (int j = 1; j < KNN; ++j) {
    unsigned int lo = c < bv[j] ? c : bv[j];
    unsigned int hi = c < bv[j] ? bv[j] : c;
    bv[j - 1] = lo; c = hi;
  }
  bv[KNN - 1] = c;
}
// u64 (key<<32 | ~col) top-9, unordered + cached min (branchy; small streams)
__device__ __forceinline__ void topk_u64(uint64_t key, uint64_t (&bk)[KNN],
                                         uint64_t& mnk, int& mns) {
  if (key > mnk) {
    #pragma unroll
    for (int j = 0; j < KNN; ++j) if (j == mns) bk[j] = key;
    mnk = bk[0]; mns = 0;
    #pragma unroll
    for (int j = 1; j < KNN; ++j) if (bk[j] < mnk) { mnk = bk[j]; mns = j; }
  }
}

// ---------------------------------------------------------------------------
// K1: y1t[b][n][o] = bn1(fc1_w @ x + fc1_b).  BIT-EXACT R4 version.
// DO NOT change the arithmetic/order here: xh/xl/sq feed a discrete top-k;
// any ulp change can flip a neighbor (verified: R5/R6 fused-norm failure).
// ---------------------------------------------------------------------------
__global__ __launch_bounds__(256) void k_fc1(const float* __restrict__ x,
                                             const float* __restrict__ w,
                                             const float* __restrict__ bias,
                                             const float* __restrict__ bn,
                                             float* __restrict__ y1t) {
  __shared__ float xs[CC * 64];  // [c][64]
  const int b = blockIdx.y, n0 = blockIdx.x * 64;
  const int t = threadIdx.x;
  for (int i = t; i < CC * 64; i += 256) {
    int c = i >> 6, nn = i & 63;
    xs[i] = x[((size_t)b * CC + c) * NN + n0 + nn];
  }
  __syncthreads();
  const int nn = t & 63;
  const int og = __builtin_amdgcn_readfirstlane(t >> 6);
  float acc[24];
  #pragma unroll
  for (int i = 0; i < 24; ++i) acc[i] = 0.f;
  for (int c = 0; c < CC; ++c) {
    float xv = xs[c * 64 + nn];
    const float* wp = w + (size_t)(og * 24) * CC + c;
    #pragma unroll
    for (int oi = 0; oi < 24; ++oi) acc[oi] = fmaf(wp[oi * CC], xv, acc[oi]);
  }
  #pragma unroll
  for (int oi = 0; oi < 24; ++oi) {
    int o = og * 24 + oi;
    float g = bn[o], be = bn[CC + o], mn = bn[2 * CC + o], vr = bn[3 * CC + o];
    float inv = g / sqrtf(vr + 1e-5f);
    float v = fmaf(acc[oi] + bias[o], inv, be - mn * inv);
    y1t[((size_t)b * NN + n0 + nn) * CC + o] = v;
  }
}

// ---------------------------------------------------------------------------
// K2: per-position L2 norm; bf16 split (hi, lo) + sq.  BIT-EXACT R4 version.
// ---------------------------------------------------------------------------
__global__ __launch_bounds__(256) void k_norm(const float* __restrict__ y1t,
                                              unsigned short* __restrict__ xh,
                                              unsigned short* __restrict__ xl,
                                              float* __restrict__ sq) {
  const int p = blockIdx.x * 256 + threadIdx.x;  // 49*256 == 12544 exactly
  const float* row = y1t + (size_t)p * CC;
  float s = 0.f;
  for (int c = 0; c < CC; c += 4) {
    float4 v = *(const float4*)(row + c);
    s += v.x * v.x; s += v.y * v.y; s += v.z * v.z; s += v.w * v.w;
  }
  float inv = 1.f / fmaxf(sqrtf(s), 1e-12f);
  float sqs = 0.f;
  unsigned short* hrow = xh + (size_t)p * CC;
  unsigned short* lrow = xl + (size_t)p * CC;
  for (int c = 0; c < CC; ++c) {
    float v = row[c] * inv;
    sqs += v * v;
    unsigned short h = f2bf(v);
    float lo = v - bf2f(h);
    hrow[c] = h;
    lrow[c] = f2bf(lo);
  }
  sq[p] = sqs;
}

// ---------------------------------------------------------------------------
// K3: two-pass kNN (unchanged from R7/R8 — passing).
// ---------------------------------------------------------------------------
__global__ __launch_bounds__(256) void k_dist(const unsigned short* __restrict__ xh,
                                              const unsigned short* __restrict__ xl,
                                              const float* __restrict__ sq,
                                              uint64_t* __restrict__ cand_k) {
  __shared__ __align__(16) unsigned short sB[2 * 64 * 104];  // 26624 B
  __shared__ __align__(16) float sqm[TILE];
  unsigned short* BsH = sB;
  unsigned short* BsL = sB + 64 * 104;
  uint64_t* sk = (uint64_t*)sB;   // pass-2 hit slots alias sB (dead then)

  const int rt = blockIdx.x, chunk = blockIdx.y, b = blockIdx.z;
  const int r0 = rt * TILE;
  const int t = threadIdx.x;
  const int lane = t & 63, w = t >> 6;
  const int m16 = lane & 15, quad = lane >> 4;
  const int mt0 = (49 * chunk) / NCH, mt1 = (49 * (chunk + 1)) / NCH;

  const int gr = r0 + w * 16 + m16;
  bf16x8 ah[3], al[3];
  {
    const unsigned short* pH = xh + ((size_t)b * NN + gr) * CC + quad * 8;
    const unsigned short* pL = xl + ((size_t)b * NN + gr) * CC + quad * 8;
    #pragma unroll
    for (int kc = 0; kc < 3; ++kc) {
      ah[kc] = *(const bf16x8*)(pH + kc * 32);
      al[kc] = *(const bf16x8*)(pL + kc * 32);
    }
  }
  const float sr = sq[b * NN + gr];

  unsigned int bv[KNN];
  #pragma unroll
  for (int j = 0; j < KNN; ++j) bv[j] = 0u;

  // ---- pass 1 ----
  const int srow_ = t >> 2, sch = t & 3;   // pow2 staging map
  for (int mt = mt0; mt < mt1; ++mt) {
    const int m0 = mt * TILE;
    __syncthreads();
    {
      const size_t rbase = ((size_t)b * NN + m0 + srow_) * CC;
      #pragma unroll
      for (int it = 0; it < 3; ++it) {
        int ch = sch + (it << 2);
        *(uint4*)&BsH[srow_ * 104 + ch * 8] = *(const uint4*)(xh + rbase + ch * 8);
        *(uint4*)&BsL[srow_ * 104 + ch * 8] = *(const uint4*)(xl + rbase + ch * 8);
      }
    }
    if (t < TILE) sqm[t] = sq[b * NN + m0 + t];
    __syncthreads();

    #pragma unroll
    for (int tt = 0; tt < 4; ++tt) {
      const int brow = (tt * 16 + m16) * 104 + quad * 8;
      f32x4 acc = {0.f, 0.f, 0.f, 0.f};
      #pragma unroll
      for (int kc = 0; kc < 3; ++kc) {
        bf16x8 bh = *(const bf16x8*)&BsH[brow + kc * 32];
        bf16x8 bl = *(const bf16x8*)&BsL[brow + kc * 32];
        acc = __builtin_amdgcn_mfma_f32_16x16x32_bf16(bh, ah[kc], acc, 0, 0, 0);
        acc = __builtin_amdgcn_mfma_f32_16x16x32_bf16(bl, ah[kc], acc, 0, 0, 0);
        acc = __builtin_amdgcn_mfma_f32_16x16x32_bf16(bh, al[kc], acc, 0, 0, 0);
      }
      float4 s4 = *(const float4*)&sqm[tt * 16 + quad * 4];
      const float sv[4] = {s4.x, s4.y, s4.z, s4.w};
      #pragma unroll
      for (int r = 0; r < 4; ++r) {
        float v = fmaf(2.f, acc[r], -sr) - sv[r];
        chain9(fmono(v), bv);
      }
    }
  }
  __syncthreads();   // all pass-1 LDS reads done before sk aliases sB

  // ---- pass 2 ----
  const unsigned int theta = bv[0];
  uint64_t* myslots = sk + ((size_t)(w * 16 + m16) * 4 + quad) * KNN;
  #pragma unroll
  for (int j = 0; j < KNN; ++j) myslots[j] = 0ull;
  int cntg = 0, cntt = 0;
  for (int mt = mt0; mt < mt1; ++mt) {
    const int m0 = mt * TILE;
    #pragma unroll
    for (int tt = 0; tt < 4; ++tt) {
      const size_t brbase = ((size_t)b * NN + m0 + tt * 16 + m16) * CC + quad * 8;
      f32x4 acc = {0.f, 0.f, 0.f, 0.f};
      #pragma unroll
      for (int kc = 0; kc < 3; ++kc) {
        bf16x8 bh = *(const bf16x8*)(xh + brbase + kc * 32);
        bf16x8 bl = *(const bf16x8*)(xl + brbase + kc * 32);
        acc = __builtin_amdgcn_mfma_f32_16x16x32_bf16(bh, ah[kc], acc, 0, 0, 0);
        acc = __builtin_amdgcn_mfma_f32_16x16x32_bf16(bl, ah[kc], acc, 0, 0, 0);
        acc = __builtin_amdgcn_mfma_f32_16x16x32_bf16(bh, al[kc], acc, 0, 0, 0);
      }
      float4 s4 = *(const float4*)(sq + (size_t)b * NN + m0 + tt * 16 + quad * 4);
      const float sv[4] = {s4.x, s4.y, s4.z, s4.w};
      #pragma unroll
      for (int r = 0; r < 4; ++r) {
        float v = fmaf(2.f, acc[r], -sr) - sv[r];
        unsigned int key = fmono(v);
        if (key >= theta) {
          int col = m0 + tt * 16 + quad * 4 + r;
          uint64_t item = ((uint64_t)key << 32) | (unsigned int)~col;
          if (key > theta) {
            if (cntg + cntt == KNN && cntt > 0) --cntt;  // evict largest-col theta
            if (cntg < KNN) myslots[cntg++] = item;
          } else if (cntg + cntt < KNN) {
            myslots[(KNN - 1) - cntt] = item;            // back-fill, asc col
            ++cntt;
          }
        }
      }
    }
  }
  __syncthreads();

  if (t < TILE) {
    uint64_t fk[KNN];
    #pragma unroll
    for (int j = 0; j < KNN; ++j) fk[j] = 0ull;
    uint64_t m2 = 0ull; int m2s = 0;
    for (int qq = 0; qq < 4; ++qq)
      #pragma unroll
      for (int j = 0; j < KNN; ++j)
        topk_u64(sk[((size_t)t * 4 + qq) * KNN + j], fk, m2, m2s);
    size_t base = (((size_t)b * NCH + chunk) * NN + r0 + t) * KNN;
    #pragma unroll
    for (int j = 0; j < KNN; ++j) cand_k[base + j] = fk[j];
  }
}

// ---------------------------------------------------------------------------
// K4: parallel chunk-merge -> nn_idx (clamped).  Removes the serial 8-thread
// merge from the gather kernel's critical path.
// ---------------------------------------------------------------------------
__global__ __launch_bounds__(256) void k_nnmerge(const uint64_t* __restrict__ cand_k,
                                                 int* __restrict__ nn_idx) {
  const int p = blockIdx.x * 256 + threadIdx.x;
  const int b = p / NN, n = p % NN;
  uint64_t fk[KNN];
  #pragma unroll
  for (int j = 0; j < KNN; ++j) fk[j] = 0ull;
  uint64_t mnk = 0ull; int mns = 0;
  for (int ch = 0; ch < NCH; ++ch) {
    size_t base = (((size_t)b * NCH + ch) * NN + n) * KNN;
    #pragma unroll
    for (int j = 0; j < KNN; ++j) topk_u64(cand_k[base + j], fk, mnk, mns);
  }
  #pragma unroll
  for (int j = 0; j < KNN; ++j) {
    int v = (int)(~(unsigned int)fk[j]);
    if ((unsigned)v >= (unsigned)NN) v = 0;
    nn_idx[(size_t)p * KNN + j] = v;
  }
}

// ---------------------------------------------------------------------------
// K5a: k-free half (oc 0..95) — no gather, pure streaming GEMM over y1t.
// Same per-oc ascending-c FMA order as before -> bit-identical ymax half.
// LDS 24.8 KB -> 6 blocks/CU.  Transpose-in-LDS for coalesced stores.
// ---------------------------------------------------------------------------
__global__ __launch_bounds__(256) void k_gfree(const float* __restrict__ y1t,
                                               const float* __restrict__ gw,
                                               const float* __restrict__ gb,
                                               const float* __restrict__ bng,
                                               float* __restrict__ ymax) {
  __shared__ float ys[64 * 97];   // [pos][c] then reused as [pos][oc]
  const int b = blockIdx.y, n0 = blockIdx.x * 64, t = threadIdx.x;
  for (int i = t; i < 64 * 24; i += 256) {
    int r = i / 24, q = i % 24;
    float4 v = *(const float4*)(y1t + ((size_t)b * NN + n0 + r) * CC + q * 4);
    float* d = &ys[r * 97 + q * 4];
    d[0] = v.x; d[1] = v.y; d[2] = v.z; d[3] = v.w;
  }
  __syncthreads();
  const int nn = t & 63;
  const int og = __builtin_amdgcn_readfirstlane(t >> 6);  // oc = og*24 .. +23
  const int cb = (og >> 1) * 48;                          // group channel base
  float acc[24];
  #pragma unroll
  for (int i = 0; i < 24; ++i) acc[i] = 0.f;
  for (int c = 0; c < 48; ++c) {
    float xv = ys[nn * 97 + cb + c];
    const float* wp = gw + (size_t)(og * 24) * 48 + c;    // wave-uniform s_loads
    #pragma unroll
    for (int oi = 0; oi < 24; ++oi) acc[oi] = fmaf(wp[oi * 48], xv, acc[oi]);
  }
  #pragma unroll
  for (int oi = 0; oi < 24; ++oi) {
    int oc = og * 24 + oi;
    float g = bng[oc], be = bng[C2 + oc], mn = bng[2 * C2 + oc], vr = bng[3 * C2 + oc];
    float inv = g / sqrtf(vr + 1e-5f);
    acc[oi] = fmaxf(fmaf(acc[oi] + gb[oc], inv, be - mn * inv), 0.f);
  }
  __syncthreads();   // all ys reads done before transpose reuse
  #pragma unroll
  for (int oi = 0; oi < 24; ++oi) ys[nn * 97 + og * 24 + oi] = acc[oi];
  __syncthreads();
  for (int i = t; i < 64 * 24; i += 256) {
    int r = i / 24, q = i % 24;
    const float* s = &ys[r * 97 + q * 4];
    float4 v = make_float4(s[0], s[1], s[2], s[3]);
    *(float4*)(ymax + ((size_t)b * NN + n0 + r) * C2 + q * 4) = v;
  }
}

// ---------------------------------------------------------------------------
// K5b: k-dependent half (oc 96..191): gather + conv + bn + relu + max over K.
// LDS 49.6 KB -> 3 blocks/CU.  fj stride 9 (odd) -> staging writes hit 32
// distinct banks (stride 12 was 8-way: gcd(12,32)=4).  Compute reads are
// 2-4-address broadcasts (free).  XCD-aware swizzle: each XCD (~bx%8) works
// one batch so its 1.2 MB y1t gather set lives in its 4 MB L2.
// ---------------------------------------------------------------------------
__global__ __launch_bounds__(256) void k_gdep(const float* __restrict__ y1t,
                                              const int* __restrict__ nn_idx,
                                              const float* __restrict__ gw,
                                              const float* __restrict__ gb,
                                              const float* __restrict__ bng,
                                              float* __restrict__ ymax) {
  __shared__ float wlB[48 * 97];          // [c][oc-96], bank (c+o)%32
  __shared__ float xi[PT * CC];
  __shared__ float fj[PT * CC * KNN];     // [(p*96+cc)*9 + k]
  __shared__ int idxl[PT * KNN];
  const int bx = blockIdx.x;
  const int xcd = bx & 7;
  const int b0 = xcd >> 1;                               // batch per XCD-pair
  const int chunk = ((bx >> 3) << 1) | (xcd & 1);        // 0..391
  const size_t p0g = (size_t)b0 * NN + chunk * PT;
  const int t = threadIdx.x;

  for (int i = t; i < 96 * 48; i += 256) {
    int o = i / 48, c = i % 48;
    wlB[c * 97 + o] = gw[96 * 48 + i];
  }
  for (int i = t; i < PT * CC; i += 256) xi[i] = y1t[p0g * CC + i];
  if (t < PT * KNN) idxl[t] = nn_idx[p0g * KNN + t];
  __syncthreads();

  for (int i = t; i < PT * KNN * CC; i += 256) {
    int pk = i / CC, cc = i % CC;
    int p = pk / KNN, k = pk % KNN;
    int j = idxl[p * KNN + k];
    fj[(p * CC + cc) * KNN + k] =
        y1t[((size_t)b0 * NN + j) * CC + cc] - xi[p * CC + cc];
  }
  __syncthreads();

  const int p = t >> 5, l = t & 31;
  float* orow = ymax + (p0g + p) * C2;
  const float* fp = fj + (size_t)p * CC * KNN;
  const bool oc1A = (l < 16);   // oc1 = 128+l: group 2 (cc 0..47) iff l<16

  float acc0[KNN], acc1[KNN], acc2[KNN];
  #pragma unroll
  for (int k = 0; k < KNN; ++k) { acc0[k] = 0.f; acc1[k] = 0.f; acc2[k] = 0.f; }
  for (int c = 0; c < 48; ++c) {
    const float* wr = wlB + c * 97;
    float w0 = wr[l], w1 = wr[32 + l], w2 = wr[64 + l];
    const float* fA = fp + c * KNN;          // cc = c      (group 2 inputs)
    const float* fB = fp + (48 + c) * KNN;   // cc = 48+c   (group 3 inputs)
    #pragma unroll
    for (int k = 0; k < KNN; ++k) {
      float a = fA[k], bb = fB[k];
      acc0[k] = fmaf(w0, a, acc0[k]);
      acc1[k] = fmaf(w1, oc1A ? a : bb, acc1[k]);
      acc2[k] = fmaf(w2, bb, acc2[k]);
    }
  }
  const int ocs[3] = {96 + l, 128 + l, 160 + l};
  #pragma unroll
  for (int oo = 0; oo < 3; ++oo) {
    int oc = ocs[oo];
    const float* ac = (oo == 0) ? acc0 : (oo == 1) ? acc1 : acc2;
    float g = bng[oc], be = bng[C2 + oc], mn = bng[2 * C2 + oc], vr = bng[3 * C2 + oc];
    float inv = g / sqrtf(vr + 1e-5f), sh = be - mn * inv, bs = gb[oc], m = 0.f;
    #pragma unroll
    for (int k = 0; k < KNN; ++k) m = fmaxf(m, fmaxf(fmaf(ac[k] + bs, inv, sh), 0.f));
    orow[oc] = m;
  }
}

// ---------------------------------------------------------------------------
// K6: out = bn2(fc2_w @ ymax + fc2_b) + x
// ---------------------------------------------------------------------------
__global__ __launch_bounds__(256) void k_fc2(const float* __restrict__ ymax,
                                             const float* __restrict__ w2,
                                             const float* __restrict__ b2,
                                             const float* __restrict__ bn2,
                                             const float* __restrict__ xin,
                                             float* __restrict__ out) {
  __shared__ float ys[64 * 193];
  const int b = blockIdx.y, n0 = blockIdx.x * 64, t = threadIdx.x;
  for (int i = t; i < 64 * C2; i += 256) {
    int nn = i / C2, c2 = i % C2;
    ys[nn * 193 + c2] = ymax[((size_t)b * NN + n0 + nn) * C2 + c2];
  }
  __syncthreads();
  const int nn = t & 63;
  const int og = __builtin_amdgcn_readfirstlane(t >> 6);
  float acc[24];
  #pragma unroll
  for (int i = 0; i < 24; ++i) acc[i] = 0.f;
  const float* yrow = ys + nn * 193;
  for (int c2 = 0; c2 < C2; ++c2) {
    float yv = yrow[c2];
    const float* wp = w2 + (size_t)(og * 24) * C2 + c2;
    #pragma unroll
    for (int oi = 0; oi < 24; ++oi) acc[oi] = fmaf(wp[oi * C2], yv, acc[oi]);
  }
  #pragma unroll
  for (int oi = 0; oi < 24; ++oi) {
    int o = og * 24 + oi;
    float g = bn2[o], be = bn2[CC + o], mn = bn2[2 * CC + o], vr = bn2[3 * CC + o];
    float inv = g / sqrtf(vr + 1e-5f);
    float v = fmaf(acc[oi] + b2[o], inv, be - mn * inv);
    size_t off = ((size_t)b * CC + o) * NN + n0 + nn;
    out[off] = v + xin[off];
  }
}

// ---------------------------------------------------------------------------
extern "C" void kernel_launch(void* const* d_in, const int* in_sizes, int n_in,
                              void* d_out, int out_size, void* d_ws, size_t ws_size,
                              hipStream_t stream) {
  const float* x     = (const float*)d_in[0];
  const float* fc1_w = (const float*)d_in[1];
  const float* fc1_b = (const float*)d_in[2];
  const float* bn1   = (const float*)d_in[3];
  const float* gc_w  = (const float*)d_in[4];
  const float* gc_b  = (const float*)d_in[5];
  const float* bng   = (const float*)d_in[6];
  const float* fc2_w = (const float*)d_in[7];
  const float* fc2_b = (const float*)d_in[8];
  const float* bn2   = (const float*)d_in[9];
  float* out = (float*)d_out;

  const size_t BNC = (size_t)BN_ * NN * CC;
  float* ws = (float*)d_ws;
  float* y1t = ws;                                   // B*N*C fp32
  unsigned short* xh = (unsigned short*)(y1t + BNC); // B*N*C bf16 hi
  unsigned short* xl = xh + BNC;                     // B*N*C bf16 lo
  float* sq     = ws + 2 * BNC;                      // B*N
  float* ymax   = sq + (size_t)BN_ * NN;             // B*N*C2
  uint64_t* cand_k = (uint64_t*)(ymax + (size_t)BN_ * NN * C2);  // B*NCH*N*9 u64
  int* nnidx = (int*)(cand_k + (size_t)BN_ * NCH * NN * KNN);    // B*N*9

  k_fc1<<<dim3(NN / 64, BN_), 256, 0, stream>>>(x, fc1_w, fc1_b, bn1, y1t);
  k_norm<<<dim3((BN_ * NN) / 256), 256, 0, stream>>>(y1t, xh, xl, sq);
  k_dist<<<dim3(NN / TILE, NCH, BN_), 256, 0, stream>>>(xh, xl, sq, cand_k);
  k_nnmerge<<<dim3((BN_ * NN) / 256), 256, 0, stream>>>(cand_k, nnidx);
  k_gfree<<<dim3(NN / 64, BN_), 256, 0, stream>>>(y1t, gc_w, gc_b, bng, ymax);
  k_gdep<<<dim3((BN_ * NN) / PT), 256, 0, stream>>>(y1t, nnidx, gc_w, gc_b, bng, ymax);
  k_fc2<<<dim3(NN / 64, BN_), 256, 0, stream>>>(ymax, fc2_w, fc2_b, bn2, x, out);
}